// Round 4
// baseline (237.332 us; speedup 1.0000x reference)
//
#include <hip/hip_runtime.h>

typedef __bf16 bf16x8 __attribute__((ext_vector_type(8)));
typedef float  f32x4  __attribute__((ext_vector_type(4)));

#define B_   8
#define N_   4096
#define D_   256

// Fragment-major layout: frag_id = (b*256 + g16)*8 + kt, frag = 64 lanes x 16B.
// Lane l of frag(g16,kt) holds P[g16*16 + (l&15)][kt*32 + (l>>4)*8 .. +8]
// -- byte-identical per-lane content to the round-3 verified LDS fragments.

// One wave per 16-row group: fp32 -> bf16 convert into fragment-major layout
// (identity per-lane permutation), squared-norms of rounded values, min-init.
__global__ __launch_bounds__(256) void prep_kernel(
    const float* __restrict__ x, const float* __restrict__ y,
    __bf16* __restrict__ Xf, __bf16* __restrict__ Yf,
    float* __restrict__ xx, float* __restrict__ yy,
    unsigned* __restrict__ rowmin, unsigned* __restrict__ colmin,
    float* __restrict__ out)
{
  if (blockIdx.x == 0 && threadIdx.x == 0) out[0] = 0.f;  // for reduce atomicAdd
  int wid  = (blockIdx.x << 2) + (threadIdx.x >> 6);      // 0..4095
  int lane = threadIdx.x & 63;
  int lcol = lane & 15, quad = lane >> 4;

  const float* src; __bf16* dst; float* nrm; unsigned* mn; int g;
  if (wid < 2048) { g = wid;        src = x; dst = Xf; nrm = xx; mn = rowmin; }
  else            { g = wid - 2048; src = y; dst = Yf; nrm = yy; mn = colmin; }

  const int row = (g << 4) + lcol;                 // global row (spans batches)
  const float* rp = src + (size_t)row * D_;
  float s = 0.f;
#pragma unroll
  for (int kt = 0; kt < 8; ++kt) {
    float4 lo = *(const float4*)(rp + kt * 32 + quad * 8);
    float4 hi = *(const float4*)(rp + kt * 32 + quad * 8 + 4);
    __bf16 b0 = (__bf16)lo.x, b1 = (__bf16)lo.y, b2 = (__bf16)lo.z, b3 = (__bf16)lo.w;
    __bf16 b4 = (__bf16)hi.x, b5 = (__bf16)hi.y, b6 = (__bf16)hi.z, b7 = (__bf16)hi.w;
    bf16x8 f = {b0, b1, b2, b3, b4, b5, b6, b7};
    *(bf16x8*)(dst + (((size_t)g * 8 + kt) << 9) + lane * 8) = f;   // coalesced b128
    float f0 = (float)b0, f1 = (float)b1, f2 = (float)b2, f3 = (float)b3;
    float f4 = (float)b4, f5 = (float)b5, f6 = (float)b6, f7 = (float)b7;
    s += f0*f0 + f1*f1 + f2*f2 + f3*f3 + f4*f4 + f5*f5 + f6*f6 + f7*f7;
  }
  s += __shfl_xor(s, 16, 64);      // fold quads: every lane gets its row's sum
  s += __shfl_xor(s, 32, 64);
  if      (quad == 0) nrm[row] = s;
  else if (quad == 1) mn[row]  = 0x7f800000u;      // +inf as uint
}

// Barrier-free register GEMM. Block: 128 rows x 1024 cols; 4 waves row-stacked,
// wave = 32 rows (af[8][2] in registers) x all 1024 cols in 32-col steps.
// A and B fragments loaded straight from global (fragment-major, coalesced
// dwordx4) -> no LDS operands, no staging, ZERO barriers in the main loop;
// compiler pipelines loads with fine-grained vmcnt (AITER pattern).
__global__ __launch_bounds__(256, 4) void chamfer_gemm(
    const __bf16* __restrict__ Xf, const __bf16* __restrict__ Yf,
    const float* __restrict__ xx, const float* __restrict__ yy,
    unsigned* __restrict__ rowmin, unsigned* __restrict__ colmin)
{
  __shared__ unsigned cmin_s[1024];            // col-min table (4 KB, only LDS)

  const int bid = blockIdx.x;
  const int b   = bid & 7;                     // batch == XCD (L2 locality)
  const int rt  = (bid >> 3) & 31;
  const int cq  = bid >> 8;                    // 0..3
  const int n0  = rt * 128;

  const int t = threadIdx.x, lane = t & 63, wave = t >> 6;
  const int quad = lane >> 4, lcol = lane & 15;

#pragma unroll
  for (int i = 0; i < 4; ++i) cmin_s[t + i * 256] = 0x7f800000u;

  const bf16x8* Xfv = (const bf16x8*)Xf;       // frag-major: idx = frag_id*64+lane
  const bf16x8* Yfv = (const bf16x8*)Yf;

  // A fragments -> registers (one-time, 16 coalesced b128 loads)
  bf16x8 af[8][2];
#pragma unroll
  for (int i = 0; i < 2; ++i)
#pragma unroll
    for (int kt = 0; kt < 8; ++kt)
      af[kt][i] = Xfv[(((size_t)(b * 256 + rt * 8 + wave * 2 + i) * 8 + kt) << 6) + lane];

  float xv[2][4], rmin[2][4];
  const float* xxp = xx + b * N_ + n0 + wave * 32;
#pragma unroll
  for (int i = 0; i < 2; ++i)
#pragma unroll
    for (int r = 0; r < 4; ++r) {
      xv[i][r] = xxp[i * 16 + quad * 4 + r];
      rmin[i][r] = 1e30f;
    }

  __syncthreads();   // cmin_s init visible; only barrier before the flush

  const float* yyp = yy + b * N_ + cq * 1024;
  const size_t cgbase = (size_t)(b * 256 + cq * 64);

  for (int ct = 0; ct < 32; ++ct) {
    const size_t f0 = ((cgbase + ct * 2 + 0) * 8) << 6;   // frag idx base, j=0
    const size_t f1 = ((cgbase + ct * 2 + 1) * 8) << 6;   // j=1
    float yv0 = yyp[ct * 32 + lcol];
    float yv1 = yyp[ct * 32 + 16 + lcol];

    f32x4 acc[2][2] = {};
#pragma unroll
    for (int kt = 0; kt < 8; ++kt) {
      bf16x8 bf0 = Yfv[f0 + (kt << 6) + lane];
      bf16x8 bf1 = Yfv[f1 + (kt << 6) + lane];
      acc[0][0] = __builtin_amdgcn_mfma_f32_16x16x32_bf16(af[kt][0], bf0, acc[0][0], 0, 0, 0);
      acc[1][0] = __builtin_amdgcn_mfma_f32_16x16x32_bf16(af[kt][1], bf0, acc[1][0], 0, 0, 0);
      acc[0][1] = __builtin_amdgcn_mfma_f32_16x16x32_bf16(af[kt][0], bf1, acc[0][1], 0, 0, 0);
      acc[1][1] = __builtin_amdgcn_mfma_f32_16x16x32_bf16(af[kt][1], bf1, acc[1][1], 0, 0, 0);
    }

    // epilogue: C/D layout row = i*16 + quad*4 + r, col = j*16 + lcol
#pragma unroll
    for (int j = 0; j < 2; ++j) {
      float yv = j ? yv1 : yv0;
      float cm = 1e30f;
#pragma unroll
      for (int i = 0; i < 2; ++i)
#pragma unroll
        for (int r = 0; r < 4; ++r) {
          float a = acc[i][j][r];
          rmin[i][r] = fminf(rmin[i][r], __builtin_fmaf(-2.0f, a, yv));
          cm         = fminf(cm,         __builtin_fmaf(-2.0f, a, xv[i][r]));
        }
      cm = fminf(cm, __shfl_xor(cm, 16, 64));
      cm = fminf(cm, __shfl_xor(cm, 32, 64));
      if (quad == 0)
        atomicMin(&cmin_s[ct * 32 + j * 16 + lcol], __float_as_uint(cm + yv));
    }
  }

  // rowmin: one global atomic set per block
#pragma unroll
  for (int i = 0; i < 2; ++i)
#pragma unroll
    for (int r = 0; r < 4; ++r) {
      float v = xv[i][r] + rmin[i][r];
#pragma unroll
      for (int m = 1; m < 16; m <<= 1) v = fminf(v, __shfl_xor(v, m, 64));
      if (lcol == 0)
        atomicMin(rowmin + b * N_ + n0 + wave * 32 + i * 16 + quad * 4 + r,
                  __float_as_uint(v));
    }

  __syncthreads();
  // colmin: flush LDS table to global
#pragma unroll
  for (int i = 0; i < 4; ++i) {
    int idx = t + i * 256;
    atomicMin(colmin + b * N_ + cq * 1024 + idx, cmin_s[idx]);
  }
}

// 64 blocks x 256 threads: 16384 uint4 = 65536 mins; wave-reduce + atomicAdd.
__global__ __launch_bounds__(256) void reduce_kernel(
    const unsigned* __restrict__ mins,   // rowmin then colmin, contiguous
    float* __restrict__ out)
{
  int idx = blockIdx.x * 256 + threadIdx.x;
  uint4 u = ((const uint4*)mins)[idx];
  float s = __uint_as_float(u.x) + __uint_as_float(u.y)
          + __uint_as_float(u.z) + __uint_as_float(u.w);
#pragma unroll
  for (int m = 1; m < 64; m <<= 1) s += __shfl_xor(s, m, 64);
  if ((threadIdx.x & 63) == 0) atomicAdd(out, s);
}

extern "C" void kernel_launch(void* const* d_in, const int* in_sizes, int n_in,
                              void* d_out, int out_size, void* d_ws, size_t ws_size,
                              hipStream_t stream) {
  const float* gts   = (const float*)d_in[0];   // [8,4096,256] fp32
  const float* preds = (const float*)d_in[1];   // [8,4096,256] fp32

  char* ws = (char*)d_ws;
  const size_t XB_BYTES = (size_t)B_ * N_ * D_ * 2;     // 16 MiB each
  __bf16*   Xf     = (__bf16*)ws;
  __bf16*   Yf     = (__bf16*)(ws + XB_BYTES);
  float*    xx     = (float*)(ws + 2 * XB_BYTES);
  float*    yy     = (float*)(ws + 2 * XB_BYTES + (size_t)B_ * N_ * 4);
  unsigned* rowmin = (unsigned*)(ws + 2 * XB_BYTES + (size_t)B_ * N_ * 8);
  unsigned* colmin = (unsigned*)(ws + 2 * XB_BYTES + (size_t)B_ * N_ * 12);

  // 4096 row-groups of 16 (X then Y), one wave each -> 1024 blocks
  prep_kernel<<<1024, 256, 0, stream>>>(gts, preds, Xf, Yf, xx, yy, rowmin, colmin,
                                        (float*)d_out);

  // 8 batches x 32 row-tiles x 4 col-quarters = 1024 blocks = 4/CU exactly
  chamfer_gemm<<<1024, 256, 0, stream>>>(Xf, Yf, xx, yy, rowmin, colmin);

  reduce_kernel<<<64, 256, 0, stream>>>(rowmin, (float*)d_out);
}

// Round 5
// 171.396 us; speedup vs baseline: 1.3847x; 1.3847x over previous
//
#include <hip/hip_runtime.h>

typedef __bf16 bf16x8 __attribute__((ext_vector_type(8)));
typedef __bf16 bf16x4 __attribute__((ext_vector_type(4)));
typedef float  f32x4  __attribute__((ext_vector_type(4)));

#define B_   8
#define N_   4096
#define D_   256

// Fragment-major layout: frag_id = (b*256 + g16)*8 + kt, frag = 64 lanes x 16B.
// Lane l of frag(g16,kt) holds P[g16*16 + (l&15)][kt*32 + (l>>4)*8 .. +8]
// -- byte-identical to the round-3/4 verified fragments.

__device__ __forceinline__ void gl_lds16(const void* g, void* l) {
  __builtin_amdgcn_global_load_lds(
      (const __attribute__((address_space(1))) unsigned int*)g,
      (__attribute__((address_space(3))) unsigned int*)l, 16, 0, 0);
}

// One wave per 16-row group. Global reads are perfectly coalesced (1 KB/wave
// float4); fragment permute done via an in-wave LDS transpose (no barriers).
__global__ __launch_bounds__(256) void prep_kernel(
    const float* __restrict__ x, const float* __restrict__ y,
    __bf16* __restrict__ Xf, __bf16* __restrict__ Yf,
    float* __restrict__ xx, float* __restrict__ yy,
    unsigned* __restrict__ rowmin, unsigned* __restrict__ colmin,
    float* __restrict__ out)
{
  __shared__ __bf16 T[4][16 * 260];   // per-wave 16 rows x 256 (+4 pad) bf16
  if (blockIdx.x == 0 && threadIdx.x == 0) out[0] = 0.f;

  const int wv = threadIdx.x >> 6, lane = threadIdx.x & 63;
  const int wid = (blockIdx.x << 2) + wv;          // 0..4095

  const float* src; __bf16* dst; float* nrm; unsigned* mn; int g;
  if (wid < 2048) { g = wid;        src = x; dst = Xf; nrm = xx; mn = rowmin; }
  else            { g = wid - 2048; src = y; dst = Yf; nrm = yy; mn = colmin; }

  __bf16* tw = T[wv];
  const float* rp = src + (size_t)g * 16 * D_;
  float myn = 0.f;
#pragma unroll
  for (int r = 0; r < 16; ++r) {
    float4 v = *(const float4*)(rp + r * D_ + lane * 4);   // 1 KB contiguous
    __bf16 b0 = (__bf16)v.x, b1 = (__bf16)v.y, b2 = (__bf16)v.z, b3 = (__bf16)v.w;
    bf16x4 st = {b0, b1, b2, b3};
    *(bf16x4*)(tw + r * 260 + lane * 4) = st;
    float f0 = (float)b0, f1 = (float)b1, f2 = (float)b2, f3 = (float)b3;
    float s = f0*f0 + f1*f1 + f2*f2 + f3*f3;
#pragma unroll
    for (int m = 1; m < 64; m <<= 1) s += __shfl_xor(s, m, 64);
    if (lane == r) myn = s;            // row-r norm parked in lane r
  }
  if (lane < 16)                nrm[g * 16 + lane] = myn;
  else if (lane < 32)           mn[g * 16 + lane - 16] = 0x7f800000u;  // +inf

  // fragment-order readback (row = lane&15, k-octet = lane>>4) + coalesced store
#pragma unroll
  for (int kt = 0; kt < 8; ++kt) {
    bf16x8 f = *(const bf16x8*)(tw + (lane & 15) * 260 + kt * 32 + (lane >> 4) * 8);
    *(bf16x8*)(dst + (((size_t)g * 8 + kt) << 9) + lane * 8) = f;     // 1 KB contig
  }
}

// 64-row-wave chamfer GEMM. Block: 256 rows x 1024 cols (32 col-tiles of 32).
// 4 waves row-stacked (64 rows each); A frags live entirely in registers
// (af[8][4] = 128 VGPRs, loaded coalesced from fragment-major Xf). B staged
// to LDS (round-3 zero-conflict layout; swizzle applied to the SOURCE address
// since global_load_lds dest must be wave-uniform + lane*16), double-buffered,
// one barrier per col-tile. ds_read:MFMA = 1:4 -> LDS pipe ~20us < MFMA ~33us.
__global__ __launch_bounds__(256, 2) void chamfer_gemm(
    const __bf16* __restrict__ Xf, const __bf16* __restrict__ Yf,
    const float* __restrict__ xx, const float* __restrict__ yy,
    unsigned* __restrict__ rowmin, unsigned* __restrict__ colmin)
{
  __shared__ __align__(16) __bf16 S[2][8192];   // 2 x 16 KB B double-buffer
  __shared__ unsigned cmin_s[1024];             // 4 KB col-min table

  const int bid = blockIdx.x;
  const int b   = bid & 7;                      // batch == XCD (L2 locality)
  const int rt  = (bid >> 3) & 15;              // 16 row-tiles of 256
  const int cq  = bid >> 7;                     // 0..3 col-quarters of 1024
  const int n0  = rt * 256;
  const int m0  = cq * 1024;

  const int t = threadIdx.x, lane = t & 63, wave = t >> 6;
  const int quad = lane >> 4, lcol = lane & 15;
  const int qsw  = quad ^ ((lcol >> 1) & 3);

#pragma unroll
  for (int i = 0; i < 4; ++i) cmin_s[t + i * 256] = 0x7f800000u;

  // ---- A fragments -> registers (32 coalesced b128 loads, one-time) ----
  const bf16x8* Xfv = (const bf16x8*)Xf;
  bf16x8 af[8][4];
#pragma unroll
  for (int i = 0; i < 4; ++i) {
    const size_t gA = (size_t)(b * 256 + rt * 16 + wave * 4 + i);
#pragma unroll
    for (int kt = 0; kt < 8; ++kt)
      af[kt][i] = Xfv[((gA * 8 + kt) << 6) + lane];
  }

  float xv[4][4], rmin[4][4];
  const float* xxp = xx + b * N_ + n0 + wave * 64;
#pragma unroll
  for (int i = 0; i < 4; ++i)
#pragma unroll
    for (int r = 0; r < 4; ++r) {
      xv[i][r] = xxp[i * 16 + quad * 4 + r];
      rmin[i][r] = 1e30f;
    }

  __syncthreads();   // cmin_s init visible

  // B staging: LDS elem pos s*8 holds (kt = s>>7, c = (s>>2)&31, qs = s&3);
  // source chunk in fragment-major Yf: l = ((qs ^ ((c>>1)&3))<<4) | (c&15).
  const size_t cgbase = (size_t)(b * 256 + cq * 64);
  const __bf16* Ybase = Yf + ((cgbase * 8) << 9);
  const float*  yyp   = yy + b * N_ + m0;

#define STAGE_B(ct_, buf_)                                                   \
  {                                                                          \
    const __bf16* Ysrc = Ybase + (((size_t)(ct_) * 16) << 9);                \
    _Pragma("unroll")                                                        \
    for (int h = 0; h < 4; ++h) {                                            \
      int s  = t + h * 256;                                                  \
      int kt = s >> 7, c = (s >> 2) & 31, qs = s & 3;                        \
      int g2 = c >> 4;                                                       \
      int l  = ((qs ^ ((c >> 1) & 3)) << 4) | (c & 15);                      \
      gl_lds16(Ysrc + ((((g2 * 8 + kt) << 6) + l) << 3), (buf_) + s * 8);    \
    }                                                                        \
  }

  STAGE_B(0, S[0]);   // prefetch first tile

  for (int ct = 0; ct < 32; ++ct) {
    __syncthreads();                       // drains B(ct) prefetch
    const __bf16* curb = S[ct & 1];
    if (ct + 1 < 32) STAGE_B(ct + 1, S[(ct + 1) & 1]);

    float yv0 = yyp[ct * 32 + lcol];
    float yv1 = yyp[ct * 32 + 16 + lcol];

    f32x4 acc[4][2] = {};
#pragma unroll
    for (int kt = 0; kt < 8; ++kt) {
      bf16x8 bf0 = *(const bf16x8*)(curb + kt * 1024 + lcol * 32 + qsw * 8);
      bf16x8 bf1 = *(const bf16x8*)(curb + kt * 1024 + (16 + lcol) * 32 + qsw * 8);
#pragma unroll
      for (int i = 0; i < 4; ++i)
        acc[i][0] = __builtin_amdgcn_mfma_f32_16x16x32_bf16(af[kt][i], bf0, acc[i][0], 0, 0, 0);
#pragma unroll
      for (int i = 0; i < 4; ++i)
        acc[i][1] = __builtin_amdgcn_mfma_f32_16x16x32_bf16(af[kt][i], bf1, acc[i][1], 0, 0, 0);
    }

    // epilogue: C/D layout row = i*16 + quad*4 + r, col = j*16 + lcol
#pragma unroll
    for (int j = 0; j < 2; ++j) {
      float yv = j ? yv1 : yv0;
      float cm = 1e30f;
#pragma unroll
      for (int i = 0; i < 4; ++i)
#pragma unroll
        for (int r = 0; r < 4; ++r) {
          float a = acc[i][j][r];
          rmin[i][r] = fminf(rmin[i][r], __builtin_fmaf(-2.0f, a, yv));
          cm         = fminf(cm,         __builtin_fmaf(-2.0f, a, xv[i][r]));
        }
      cm = fminf(cm, __shfl_xor(cm, 16, 64));
      cm = fminf(cm, __shfl_xor(cm, 32, 64));
      if (quad == 0)
        atomicMin(&cmin_s[ct * 32 + j * 16 + lcol], __float_as_uint(cm + yv));
    }
  }

  // rowmin: one global atomic set per block (64 rows/wave)
#pragma unroll
  for (int i = 0; i < 4; ++i)
#pragma unroll
    for (int r = 0; r < 4; ++r) {
      float v = xv[i][r] + rmin[i][r];
#pragma unroll
      for (int m = 1; m < 16; m <<= 1) v = fminf(v, __shfl_xor(v, m, 64));
      if (lcol == 0)
        atomicMin(rowmin + b * N_ + n0 + wave * 64 + i * 16 + quad * 4 + r,
                  __float_as_uint(v));
    }

  __syncthreads();
  // colmin: flush LDS table to global
#pragma unroll
  for (int i = 0; i < 4; ++i) {
    int idx = t + i * 256;
    atomicMin(colmin + b * N_ + m0 + idx, cmin_s[idx]);
  }
#undef STAGE_B
}

// 64 blocks x 256 threads: 16384 uint4 = 65536 mins; wave-reduce + atomicAdd.
__global__ __launch_bounds__(256) void reduce_kernel(
    const unsigned* __restrict__ mins,   // rowmin then colmin, contiguous
    float* __restrict__ out)
{
  int idx = blockIdx.x * 256 + threadIdx.x;
  uint4 u = ((const uint4*)mins)[idx];
  float s = __uint_as_float(u.x) + __uint_as_float(u.y)
          + __uint_as_float(u.z) + __uint_as_float(u.w);
#pragma unroll
  for (int m = 1; m < 64; m <<= 1) s += __shfl_xor(s, m, 64);
  if ((threadIdx.x & 63) == 0) atomicAdd(out, s);
}

extern "C" void kernel_launch(void* const* d_in, const int* in_sizes, int n_in,
                              void* d_out, int out_size, void* d_ws, size_t ws_size,
                              hipStream_t stream) {
  const float* gts   = (const float*)d_in[0];   // [8,4096,256] fp32
  const float* preds = (const float*)d_in[1];   // [8,4096,256] fp32

  char* ws = (char*)d_ws;
  const size_t XB_BYTES = (size_t)B_ * N_ * D_ * 2;     // 16 MiB each
  __bf16*   Xf     = (__bf16*)ws;
  __bf16*   Yf     = (__bf16*)(ws + XB_BYTES);
  float*    xx     = (float*)(ws + 2 * XB_BYTES);
  float*    yy     = (float*)(ws + 2 * XB_BYTES + (size_t)B_ * N_ * 4);
  unsigned* rowmin = (unsigned*)(ws + 2 * XB_BYTES + (size_t)B_ * N_ * 8);
  unsigned* colmin = (unsigned*)(ws + 2 * XB_BYTES + (size_t)B_ * N_ * 12);

  // 4096 row-groups of 16 (X then Y), one wave each -> 1024 blocks
  prep_kernel<<<1024, 256, 0, stream>>>(gts, preds, Xf, Yf, xx, yy, rowmin, colmin,
                                        (float*)d_out);

  // 8 batches x 16 row-tiles(256) x 4 col-quarters(1024) = 512 blocks = 2/CU
  chamfer_gemm<<<512, 256, 0, stream>>>(Xf, Yf, xx, yy, rowmin, colmin);

  reduce_kernel<<<64, 256, 0, stream>>>(rowmin, (float*)d_out);
}

// Round 7
// 141.951 us; speedup vs baseline: 1.6719x; 1.2074x over previous
//
#include <hip/hip_runtime.h>

typedef int   i32x8 __attribute__((ext_vector_type(8)));
typedef float f32x4 __attribute__((ext_vector_type(4)));

#define B_   8
#define N_   4096
#define D_   256

// fp8 fragment-major blob layout:
//   blob[g16][kt][h] = 1 KB chunk; lane l's 16 bytes at +l*16 hold
//   P[g16*16 + (l&15)][k = kt*128 + (l>>4)*32 + h*16 .. +16]  (e4m3)
// i.e. per-lane k-contiguous 32-byte operand rows for mfma_scale 16x16x128.

__device__ __forceinline__ void gl_lds16(const void* g, void* l) {
  __builtin_amdgcn_global_load_lds(
      (const __attribute__((address_space(1))) unsigned int*)g,
      (__attribute__((address_space(3))) unsigned int*)l, 16, 0, 0);
}

// sum of squares of the 4 e4m3 bytes in w (selector must be a literal)
__device__ __forceinline__ float sq8(unsigned w) {
  float f0 = __builtin_amdgcn_cvt_f32_fp8(w, 0);
  float f1 = __builtin_amdgcn_cvt_f32_fp8(w, 1);
  float f2 = __builtin_amdgcn_cvt_f32_fp8(w, 2);
  float f3 = __builtin_amdgcn_cvt_f32_fp8(w, 3);
  return f0 * f0 + f1 * f1 + f2 * f2 + f3 * f3;
}

// One wave per 16-row group: fp32 -> fp8 e4m3 convert (coalesced 1 KB float4
// reads), in-wave LDS transpose to fragment-major, norms of DEQUANTIZED
// values accumulated during readback (2 shuffles total), min-init.
__global__ __launch_bounds__(256) void prep_kernel(
    const float* __restrict__ x, const float* __restrict__ y,
    unsigned char* __restrict__ Xf, unsigned char* __restrict__ Yf,
    float* __restrict__ xx, float* __restrict__ yy,
    unsigned* __restrict__ rowmin, unsigned* __restrict__ colmin,
    float* __restrict__ out)
{
  __shared__ unsigned char T[4][16 * 272];   // 16 rows x 256B fp8 (+16 pad)
  if (blockIdx.x == 0 && threadIdx.x == 0) out[0] = 0.f;

  const int wv = threadIdx.x >> 6, lane = threadIdx.x & 63;
  const int wid = (blockIdx.x << 2) + wv;          // 0..4095

  const float* src; unsigned char* dst; float* nrm; unsigned* mn; int g;
  if (wid < 2048) { g = wid;        src = x; dst = Xf; nrm = xx; mn = rowmin; }
  else            { g = wid - 2048; src = y; dst = Yf; nrm = yy; mn = colmin; }

  unsigned char* tw = T[wv];
  const float* rp = src + (size_t)g * 16 * D_;
#pragma unroll
  for (int r = 0; r < 16; ++r) {
    float4 v = *(const float4*)(rp + r * D_ + lane * 4);   // 1 KB contiguous
    unsigned u = __builtin_amdgcn_cvt_pk_fp8_f32(v.x, v.y, 0, 0);
    u = __builtin_amdgcn_cvt_pk_fp8_f32(v.z, v.w, u, 1);   // bytes = x,y,z,w
    *(unsigned*)(tw + r * 272 + lane * 4) = u;
  }
  __syncthreads();

  // fragment-order readback: row = lane&15, k-base = (lane>>4)*32
  float s = 0.f;
  const int row = lane & 15, ko = (lane >> 4) * 32;
#pragma unroll
  for (int kt = 0; kt < 2; ++kt)
#pragma unroll
    for (int h = 0; h < 2; ++h) {
      uint4 c = *(const uint4*)(tw + row * 272 + kt * 128 + ko + h * 16);
      s += sq8(c.x) + sq8(c.y) + sq8(c.z) + sq8(c.w);
      *(uint4*)(dst + ((((size_t)g * 2 + kt) * 2 + h) << 10) + lane * 16) = c;
    }
  s += __shfl_xor(s, 16, 64);   // fold quads: row (lane&15)'s full norm
  s += __shfl_xor(s, 32, 64);
  if      (lane < 16) nrm[g * 16 + lane] = s;
  else if (lane < 32) mn[g * 16 + lane - 16] = 0x7f800000u;   // +inf
}

// MX-fp8 chamfer GEMM (mfma_scale_f32_16x16x128_f8f6f4, scales = 1.0).
// Block: 256 rows x 1024 cols; 4 waves x 64 rows; af[4][2] (v8i32) in regs;
// B staged per 32-col tile (8 KB), double-buffered, one barrier per tile.
// 16 MFMAs/ct/wave (K=128 x 2). C/D layout identical to 16x16x32 bf16
// (shape-determined, m121-128) -> epilogue unchanged from round 5.
__global__ __launch_bounds__(256, 2) void chamfer_gemm(
    const unsigned char* __restrict__ Xf, const unsigned char* __restrict__ Yf,
    const float* __restrict__ xx, const float* __restrict__ yy,
    unsigned* __restrict__ rowmin, unsigned* __restrict__ colmin)
{
  __shared__ __align__(16) unsigned char S[2][8192];   // B double-buffer
  __shared__ unsigned cmin_s[1024];                    // col-min table

  const int bid = blockIdx.x;
  const int b   = bid & 7;                   // batch == XCD (L2 locality)
  const int rt  = (bid >> 3) & 15;           // 16 row-tiles of 256
  const int cq  = bid >> 7;                  // 0..3 col-quarters of 1024
  const int n0  = rt * 256;
  const int m0  = cq * 1024;

  const int t = threadIdx.x, lane = t & 63, wave = t >> 6;
  const int quad = lane >> 4, lcol = lane & 15;

#pragma unroll
  for (int i = 0; i < 4; ++i) cmin_s[t + i * 256] = 0x7f800000u;

  // ---- A fragments -> registers (coalesced dwordx4 from fragment blob) ----
  i32x8 af[4][2];
#pragma unroll
  for (int i = 0; i < 4; ++i) {
    const size_t g = (size_t)(b * 256 + rt * 16 + wave * 4 + i);
#pragma unroll
    for (int kt = 0; kt < 2; ++kt) {
      const uint4* p = (const uint4*)(Xf + ((g * 2 + kt) << 11));
      uint4 lo = p[lane];        // h=0
      uint4 hi = p[64 + lane];   // h=1
      i32x8 a;
      a[0] = lo.x; a[1] = lo.y; a[2] = lo.z; a[3] = lo.w;
      a[4] = hi.x; a[5] = hi.y; a[6] = hi.z; a[7] = hi.w;
      af[i][kt] = a;
    }
  }

  float xv[4][4], rmin[4][4];
  const float* xxp = xx + b * N_ + n0 + wave * 64;
#pragma unroll
  for (int i = 0; i < 4; ++i)
#pragma unroll
    for (int r = 0; r < 4; ++r) {
      xv[i][r] = xxp[i * 16 + quad * 4 + r];
      rmin[i][r] = 1e30f;
    }

  __syncthreads();   // cmin_s init visible

  // B staging: LDS chunk cd = kt*4 + h*2 + j at cd*1024; slot s = t + h2*256
  // -> cd = s>>6 (wave-uniform), lane slot = s&63. Source chunk is a
  // contiguous 1 KB of the fragment blob -> perfectly coalesced.
  const unsigned char* Ybase = Yf + (((size_t)(b * 256 + cq * 64) * 2) << 11);
  const float* yyp = yy + b * N_ + m0;

#define STAGE_B(ct_, buf_)                                                    \
  {                                                                           \
    const unsigned char* Ysrc = Ybase + ((size_t)(ct_) << 13);  /* 2 g16 */   \
    _Pragma("unroll")                                                         \
    for (int h2 = 0; h2 < 2; ++h2) {                                          \
      int s  = t + h2 * 256;                                                  \
      int cd = s >> 6, ln = s & 63;                                           \
      int kt = cd >> 2, hh = (cd >> 1) & 1, jj = cd & 1;                      \
      gl_lds16(Ysrc + jj * 4096 + kt * 2048 + hh * 1024 + ln * 16,            \
               (buf_) + s * 16);                                              \
    }                                                                         \
  }

  STAGE_B(0, S[0]);   // prefetch first tile

  for (int ct = 0; ct < 32; ++ct) {
    __syncthreads();                       // drains B(ct) prefetch
    const unsigned char* curb = S[ct & 1];
    if (ct + 1 < 32) STAGE_B(ct + 1, S[(ct + 1) & 1]);

    float yv0 = yyp[ct * 32 + lcol];
    float yv1 = yyp[ct * 32 + 16 + lcol];

    // B fragments: bq[j][kt] from chunks (kt, h, j)
    i32x8 bq[2][2];
#pragma unroll
    for (int j = 0; j < 2; ++j)
#pragma unroll
      for (int kt = 0; kt < 2; ++kt) {
        uint4 lo = *(const uint4*)(curb + (kt * 4 + 0 + j) * 1024 + lane * 16);
        uint4 hi = *(const uint4*)(curb + (kt * 4 + 2 + j) * 1024 + lane * 16);
        i32x8 v;
        v[0] = lo.x; v[1] = lo.y; v[2] = lo.z; v[3] = lo.w;
        v[4] = hi.x; v[5] = hi.y; v[6] = hi.z; v[7] = hi.w;
        bq[j][kt] = v;
      }

    f32x4 acc[4][2] = {};
#pragma unroll
    for (int kt = 0; kt < 2; ++kt)
#pragma unroll
      for (int i = 0; i < 4; ++i)
#pragma unroll
        for (int j = 0; j < 2; ++j)
          acc[i][j] = __builtin_amdgcn_mfma_scale_f32_16x16x128_f8f6f4(
              af[i][kt], bq[j][kt], acc[i][j],
              0, 0,        // cbsz = A fmt e4m3, blgp = B fmt e4m3
              0, 127,      // scale A: opsel 0, e8m0 127 = 1.0
              0, 127);     // scale B

    // ---- epilogue: C/D row = i*16 + quad*4 + r, col = j*16 + lcol ----
#pragma unroll
    for (int j = 0; j < 2; ++j) {
      float yv = j ? yv1 : yv0;
      float cm = 1e30f;
#pragma unroll
      for (int i = 0; i < 4; ++i)
#pragma unroll
        for (int r = 0; r < 4; ++r) {
          float a = acc[i][j][r];
          rmin[i][r] = fminf(rmin[i][r], __builtin_fmaf(-2.0f, a, yv));
          cm         = fminf(cm,         __builtin_fmaf(-2.0f, a, xv[i][r]));
        }
      cm = fminf(cm, __shfl_xor(cm, 16, 64));
      cm = fminf(cm, __shfl_xor(cm, 32, 64));
      if (quad == 0)
        atomicMin(&cmin_s[ct * 32 + j * 16 + lcol], __float_as_uint(cm + yv));
    }
  }

  // rowmin: one global atomic set per block (64 rows/wave)
#pragma unroll
  for (int i = 0; i < 4; ++i)
#pragma unroll
    for (int r = 0; r < 4; ++r) {
      float v = xv[i][r] + rmin[i][r];
#pragma unroll
      for (int m = 1; m < 16; m <<= 1) v = fminf(v, __shfl_xor(v, m, 64));
      if (lcol == 0)
        atomicMin(rowmin + b * N_ + n0 + wave * 64 + i * 16 + quad * 4 + r,
                  __float_as_uint(v));
    }

  __syncthreads();
  // colmin: flush LDS table to global
#pragma unroll
  for (int i = 0; i < 4; ++i) {
    int idx = t + i * 256;
    atomicMin(colmin + b * N_ + m0 + idx, cmin_s[idx]);
  }
#undef STAGE_B
}

// 64 blocks x 256 threads: 16384 uint4 = 65536 mins; wave-reduce + atomicAdd.
__global__ __launch_bounds__(256) void reduce_kernel(
    const unsigned* __restrict__ mins,   // rowmin then colmin, contiguous
    float* __restrict__ out)
{
  int idx = blockIdx.x * 256 + threadIdx.x;
  uint4 u = ((const uint4*)mins)[idx];
  float s = __uint_as_float(u.x) + __uint_as_float(u.y)
          + __uint_as_float(u.z) + __uint_as_float(u.w);
#pragma unroll
  for (int m = 1; m < 64; m <<= 1) s += __shfl_xor(s, m, 64);
  if ((threadIdx.x & 63) == 0) atomicAdd(out, s);
}

extern "C" void kernel_launch(void* const* d_in, const int* in_sizes, int n_in,
                              void* d_out, int out_size, void* d_ws, size_t ws_size,
                              hipStream_t stream) {
  const float* gts   = (const float*)d_in[0];   // [8,4096,256] fp32
  const float* preds = (const float*)d_in[1];   // [8,4096,256] fp32

  char* ws = (char*)d_ws;
  const size_t XB_BYTES = (size_t)B_ * N_ * D_;         // 8 MiB each (fp8)
  unsigned char* Xf     = (unsigned char*)ws;
  unsigned char* Yf     = (unsigned char*)(ws + XB_BYTES);
  float*    xx     = (float*)(ws + 2 * XB_BYTES);
  float*    yy     = (float*)(ws + 2 * XB_BYTES + (size_t)B_ * N_ * 4);
  unsigned* rowmin = (unsigned*)(ws + 2 * XB_BYTES + (size_t)B_ * N_ * 8);
  unsigned* colmin = (unsigned*)(ws + 2 * XB_BYTES + (size_t)B_ * N_ * 12);

  // 4096 row-groups of 16 (X then Y), one wave each -> 1024 blocks
  prep_kernel<<<1024, 256, 0, stream>>>(gts, preds, Xf, Yf, xx, yy, rowmin, colmin,
                                        (float*)d_out);

  // 8 batches x 16 row-tiles(256) x 4 col-quarters(1024) = 512 blocks
  chamfer_gemm<<<512, 256, 0, stream>>>(Xf, Yf, xx, yy, rowmin, colmin);

  reduce_kernel<<<64, 256, 0, stream>>>(rowmin, (float*)d_out);
}